// Round 1
// baseline (309.892 us; speedup 1.0000x reference)
//
#include <hip/hip_runtime.h>
#include <hip/hip_bf16.h>

#define NCH 128   // IN_CH == HID == 128

// ---------------------------------------------------------------------------
// K0: detect edge_index storage width. If stored as int64 (little-endian,
// values < 2^31), every odd int32 word of the first 64 elements is 0.
__global__ void k_detect(const int* __restrict__ ei, int* __restrict__ flag) {
    int v = ei[2 * threadIdx.x + 1];
    unsigned long long b = __ballot(v != 0);
    if (threadIdx.x == 0) *flag = (b == 0ULL) ? 1 : 0;
}

// K1: histogram of destination degrees
__global__ void k_hist(const int* __restrict__ ei32, const long long* __restrict__ ei64,
                       const int* __restrict__ flag, int* __restrict__ cnt, int E) {
    int e = blockIdx.x * blockDim.x + threadIdx.x;
    if (e >= E) return;
    int dst = (*flag) ? (int)ei64[(size_t)E + e] : ei32[(size_t)E + e];
    atomicAdd(&cnt[dst], 1);
}

// K2: exclusive scan of cnt -> row_start (single block, 256 threads)
__global__ void k_scan(const int* __restrict__ cnt, int* __restrict__ row_start, int N) {
    __shared__ int lds[256];
    int t = threadIdx.x;
    int chunk = (N + 255) / 256;
    int base = t * chunk;
    int sum = 0;
    for (int i = 0; i < chunk; ++i) {
        int idx = base + i;
        if (idx < N) sum += cnt[idx];
    }
    lds[t] = sum;
    __syncthreads();
    for (int off = 1; off < 256; off <<= 1) {
        int v = (t >= off) ? lds[t - off] : 0;
        __syncthreads();
        lds[t] += v;
        __syncthreads();
    }
    int run = (t == 0) ? 0 : lds[t - 1];
    for (int i = 0; i < chunk; ++i) {
        int idx = base + i;
        if (idx < N) { row_start[idx] = run; run += cnt[idx]; }
    }
    if (t == 255) row_start[N] = run;
}

// K3: fill CSR source lists
__global__ void k_fill(const int* __restrict__ ei32, const long long* __restrict__ ei64,
                       const int* __restrict__ flag, const int* __restrict__ row_start,
                       int* __restrict__ cursor, int* __restrict__ csr, int E) {
    int e = blockIdx.x * blockDim.x + threadIdx.x;
    if (e >= E) return;
    int src, dst;
    if (*flag) { src = (int)ei64[e]; dst = (int)ei64[(size_t)E + e]; }
    else       { src = ei32[e];      dst = ei32[(size_t)E + e]; }
    int pos = atomicAdd(&cursor[dst], 1);
    csr[row_start[dst] + pos] = src;
}

// K4: fused pull-aggregation + dual matmul + relu + global channel max.
// One wave handles 4 nodes; lane owns channels (2*lane, 2*lane+1).
__global__ __launch_bounds__(256) void k_agg_linmax(
    const float* __restrict__ x, const int* __restrict__ row_start,
    const int* __restrict__ csr, const float* __restrict__ Wl,
    const float* __restrict__ bl, const float* __restrict__ Wr,
    unsigned int* __restrict__ hmaxU, int N, int E) {
    const int lane = threadIdx.x & 63;
    const int wave = threadIdx.x >> 6;
    const int group = blockIdx.x * 4 + wave;
    const int ngroups = (N + 3) / 4;

    const float2* __restrict__ x2  = (const float2*)x;
    const float2* __restrict__ Wl2 = (const float2*)Wl;
    const float2* __restrict__ Wr2 = (const float2*)Wr;
    const float2* __restrict__ bl2 = (const float2*)bl;

    float2 m = make_float2(0.f, 0.f);

    if (group < ngroups) {
        int n0 = group * 4;
        int s[4], d[4];
#pragma unroll
        for (int q = 0; q < 4; ++q) {
            int n = n0 + q;
            if (n < N) { s[q] = row_start[n]; d[q] = row_start[n + 1] - s[q]; }
            else       { s[q] = 0; d[q] = 0; }
        }
        int maxd = max(max(d[0], d[1]), max(d[2], d[3]));

        float2 acc[4];
#pragma unroll
        for (int q = 0; q < 4; ++q) acc[q] = make_float2(0.f, 0.f);

        int idxv[4] = {0, 0, 0, 0};
        for (int i = 0; i < maxd; ++i) {
            int t = i & 63;
            if (t == 0) {
#pragma unroll
                for (int q = 0; q < 4; ++q) {
                    if (i < d[q]) {
                        int a = s[q] + i + lane;
                        a = (a < E) ? a : (E - 1);   // clamp (values past d[q] unused)
                        idxv[q] = csr[a];
                    }
                }
            }
#pragma unroll
            for (int q = 0; q < 4; ++q) {
                if (i < d[q]) {                       // wave-uniform branch
                    int src = __shfl(idxv[q], t);
                    float2 v = x2[src * 64 + lane];
                    acc[q].x += v.x; acc[q].y += v.y;
                }
            }
        }

        float2 xv[4];
#pragma unroll
        for (int q = 0; q < 4; ++q) {
            float sc = 1.0f / fmaxf((float)d[q], 1.0f);
            acc[q].x *= sc; acc[q].y *= sc;
            int n = n0 + q;
            xv[q] = (n < N) ? x2[n * 64 + lane] : make_float2(0.f, 0.f);
        }

        float2 o[4];
#pragma unroll
        for (int q = 0; q < 4; ++q) o[q] = bl2[lane];

        for (int j = 0; j < 64; ++j) {
            float2 wl0 = Wl2[(2 * j) * 64 + lane];
            float2 wl1 = Wl2[(2 * j + 1) * 64 + lane];
            float2 wr0 = Wr2[(2 * j) * 64 + lane];
            float2 wr1 = Wr2[(2 * j + 1) * 64 + lane];
#pragma unroll
            for (int q = 0; q < 4; ++q) {
                float ax = __shfl(acc[q].x, j);
                float ay = __shfl(acc[q].y, j);
                float xx = __shfl(xv[q].x, j);
                float xy = __shfl(xv[q].y, j);
                o[q].x += ax * wl0.x + ay * wl1.x + xx * wr0.x + xy * wr1.x;
                o[q].y += ax * wl0.y + ay * wl1.y + xx * wr0.y + xy * wr1.y;
            }
        }

#pragma unroll
        for (int q = 0; q < 4; ++q) {
            if (n0 + q < N) {
                float rx = fmaxf(o[q].x, 0.f);
                float ry = fmaxf(o[q].y, 0.f);
                m.x = fmaxf(m.x, rx);
                m.y = fmaxf(m.y, ry);
            }
        }
    }

    // block reduction across the 4 waves, then one atomicMax pair per lane
    __shared__ float2 red[4][64];
    red[wave][lane] = m;
    __syncthreads();
    if (wave == 0) {
#pragma unroll
        for (int w = 1; w < 4; ++w) {
            m.x = fmaxf(m.x, red[w][lane].x);
            m.y = fmaxf(m.y, red[w][lane].y);
        }
        // relu outputs are >= 0, so uint bit-pattern order == float order
        atomicMax(&hmaxU[2 * lane],     __float_as_uint(m.x));
        atomicMax(&hmaxU[2 * lane + 1], __float_as_uint(m.y));
    }
}

// K5: tiny MLP head (single block, 128 threads)
__global__ void k_head(const float* __restrict__ x, const float* __restrict__ hmax,
                       const float* __restrict__ W0, const float* __restrict__ b0,
                       const float* __restrict__ W1, const float* __restrict__ b1,
                       const float* __restrict__ W2, const float* __restrict__ b2,
                       float* __restrict__ out) {
    __shared__ float s_cat[2 * NCH];
    __shared__ float s_h1[NCH];
    int t = threadIdx.x;  // 0..127
    float acc = b0[t];
    for (int k = 0; k < NCH; ++k) acc += x[k] * W0[k * NCH + t];
    s_cat[t] = fmaxf(acc, 0.f);       // news
    s_cat[NCH + t] = hmax[t];         // pooled h
    __syncthreads();
    float h = b1[t];
    for (int k = 0; k < 2 * NCH; ++k) h += s_cat[k] * W1[k * NCH + t];
    s_h1[t] = fmaxf(h, 0.f);
    __syncthreads();
    if (t < 2) {
        float o = b2[t];
        for (int k = 0; k < NCH; ++k) o += s_h1[k] * W2[k * 2 + t];
        out[t] = o;
    }
}

extern "C" void kernel_launch(void* const* d_in, const int* in_sizes, int n_in,
                              void* d_out, int out_size, void* d_ws, size_t ws_size,
                              hipStream_t stream) {
    const float* x  = (const float*)d_in[0];
    const void*  ei = d_in[1];
    const float* Wl = (const float*)d_in[2];
    const float* bl = (const float*)d_in[3];
    const float* Wr = (const float*)d_in[4];
    const float* W0 = (const float*)d_in[5];
    const float* b0 = (const float*)d_in[6];
    const float* W1 = (const float*)d_in[7];
    const float* b1 = (const float*)d_in[8];
    const float* W2 = (const float*)d_in[9];
    const float* b2 = (const float*)d_in[10];
    float* out = (float*)d_out;

    const int N = in_sizes[0] / NCH;   // 10000
    const int E = in_sizes[1] / 2;     // 640000

    // workspace layout (ints):
    // [0, N)            cnt
    // [N, 2N)           cursor
    // [2N, 2N+128)      hmax (uint-as-float)
    // [2N+128]          flag
    // [2N+132, 3N+133)  row_start
    // [3N+144, ...)     csr_src (E ints)
    int* iws       = (int*)d_ws;
    int* cnt       = iws;
    int* cursor    = iws + N;
    unsigned int* hmaxU = (unsigned int*)(iws + 2 * N);
    int* flag      = iws + 2 * N + 128;
    int* row_start = iws + 2 * N + 132;
    int* csr       = iws + 3 * N + 144;

    // zero cnt, cursor, hmax (ws is poisoned 0xAA before every call)
    hipMemsetAsync(d_ws, 0, (size_t)(2 * N + 128) * sizeof(int), stream);

    k_detect<<<1, 64, 0, stream>>>((const int*)ei, flag);
    k_hist<<<(E + 255) / 256, 256, 0, stream>>>((const int*)ei, (const long long*)ei,
                                                flag, cnt, E);
    k_scan<<<1, 256, 0, stream>>>(cnt, row_start, N);
    k_fill<<<(E + 255) / 256, 256, 0, stream>>>((const int*)ei, (const long long*)ei,
                                                flag, row_start, cursor, csr, E);
    int ngroups = (N + 3) / 4;
    k_agg_linmax<<<(ngroups + 3) / 4, 256, 0, stream>>>(x, row_start, csr, Wl, bl, Wr,
                                                        hmaxU, N, E);
    k_head<<<1, 128, 0, stream>>>(x, (const float*)hmaxU, W0, b0, W1, b1, W2, b2, out);
}

// Round 2
// 259.546 us; speedup vs baseline: 1.1940x; 1.1940x over previous
//
#include <hip/hip_runtime.h>
#include <hip/hip_bf16.h>

#define NCH 128   // IN_CH == HID == 128

// ---------------------------------------------------------------------------
// K0: detect edge_index storage width. If stored as int64 (little-endian,
// values < 2^31), every odd int32 word of the first 64 elements is 0.
__global__ void k_detect(const int* __restrict__ ei, int* __restrict__ flag) {
    int v = ei[2 * threadIdx.x + 1];
    unsigned long long b = __ballot(v != 0);
    if (threadIdx.x == 0) *flag = (b == 0ULL) ? 1 : 0;
}

// K_cast: x fp32 -> packed bf16 pairs (RNE)
__device__ inline unsigned int f2bf_pair(float lo, float hi) {
    unsigned int ul = __float_as_uint(lo);
    unsigned int uh = __float_as_uint(hi);
    ul = (ul + 0x7fffu + ((ul >> 16) & 1u)) >> 16;
    uh = (uh + 0x7fffu + ((uh >> 16) & 1u)) & 0xffff0000u;
    return (ul & 0xffffu) | uh;
}
__global__ void k_cast(const float2* __restrict__ x2, unsigned int* __restrict__ xb, int n2) {
    int i = blockIdx.x * blockDim.x + threadIdx.x;
    if (i >= n2) return;
    float2 v = x2[i];
    xb[i] = f2bf_pair(v.x, v.y);
}

// K1: histogram of destination degrees
__global__ void k_hist(const int* __restrict__ ei32, const long long* __restrict__ ei64,
                       const int* __restrict__ flag, int* __restrict__ cnt, int E) {
    int e = blockIdx.x * blockDim.x + threadIdx.x;
    if (e >= E) return;
    int dst = (*flag) ? (int)ei64[(size_t)E + e] : ei32[(size_t)E + e];
    atomicAdd(&cnt[dst], 1);
}

// K2: exclusive scan of cnt -> row_start (single block, 1024 threads)
__global__ void k_scan(const int* __restrict__ cnt, int* __restrict__ row_start, int N) {
    __shared__ int lds[1024];
    int t = threadIdx.x;
    int chunk = (N + 1023) / 1024;
    int base = t * chunk;
    int sum = 0;
    for (int i = 0; i < chunk; ++i) {
        int idx = base + i;
        if (idx < N) sum += cnt[idx];
    }
    lds[t] = sum;
    __syncthreads();
    for (int off = 1; off < 1024; off <<= 1) {
        int v = (t >= off) ? lds[t - off] : 0;
        __syncthreads();
        lds[t] += v;
        __syncthreads();
    }
    int run = (t == 0) ? 0 : lds[t - 1];
    for (int i = 0; i < chunk; ++i) {
        int idx = base + i;
        if (idx < N) { row_start[idx] = run; run += cnt[idx]; }
    }
    if (t == 1023) row_start[N] = run;
}

// K3: fill CSR source lists
__global__ void k_fill(const int* __restrict__ ei32, const long long* __restrict__ ei64,
                       const int* __restrict__ flag, const int* __restrict__ row_start,
                       int* __restrict__ cursor, int* __restrict__ csr, int E) {
    int e = blockIdx.x * blockDim.x + threadIdx.x;
    if (e >= E) return;
    int src, dst;
    if (*flag) { src = (int)ei64[e]; dst = (int)ei64[(size_t)E + e]; }
    else       { src = ei32[e];      dst = ei32[(size_t)E + e]; }
    int pos = atomicAdd(&cursor[dst], 1);
    csr[row_start[dst] + pos] = src;
}

// K4a: pull aggregation, 1 node per wave, bf16 gathers, fp32 accumulate,
// unroll-8 for 8 outstanding gathers per wave.
__global__ __launch_bounds__(256) void k_agg(
    const unsigned int* __restrict__ xb, const int* __restrict__ row_start,
    const int* __restrict__ csr, float2* __restrict__ agg, int N) {
    const int lane = threadIdx.x & 63;
    const int node = blockIdx.x * 4 + (threadIdx.x >> 6);
    if (node >= N) return;
    int s = row_start[node];
    int e = row_start[node + 1];
    int d = e - s;
    float ax = 0.f, ay = 0.f;
    for (int base = s; base < e; base += 64) {
        int cnt = min(64, e - base);
        int idx = csr[base + min(lane, cnt - 1)];
        int i = 0;
        for (; i + 8 <= cnt; i += 8) {
            int srcs[8];
#pragma unroll
            for (int j = 0; j < 8; ++j) srcs[j] = __shfl(idx, i + j);
            unsigned int us[8];
#pragma unroll
            for (int j = 0; j < 8; ++j) us[j] = xb[srcs[j] * 64 + lane];
#pragma unroll
            for (int j = 0; j < 8; ++j) {
                ax += __uint_as_float(us[j] << 16);
                ay += __uint_as_float(us[j] & 0xffff0000u);
            }
        }
        for (; i < cnt; ++i) {
            int src = __shfl(idx, i);
            unsigned int u = xb[src * 64 + lane];
            ax += __uint_as_float(u << 16);
            ay += __uint_as_float(u & 0xffff0000u);
        }
    }
    float sc = 1.0f / fmaxf((float)d, 1.0f);
    agg[node * 64 + lane] = make_float2(ax * sc, ay * sc);
}

// K4b: dense part: relu(agg@Wl + bl + x@Wr), global channel max.
// 8 nodes per wave; lane owns channels (2*lane, 2*lane+1).
__global__ __launch_bounds__(256) void k_dense(
    const float2* __restrict__ x2, const float2* __restrict__ agg2,
    const float* __restrict__ Wl, const float* __restrict__ bl,
    const float* __restrict__ Wr, unsigned int* __restrict__ hmaxU, int N) {
    const int lane = threadIdx.x & 63;
    const int wave = threadIdx.x >> 6;
    const int w = blockIdx.x * 4 + wave;
    const int n0 = w * 8;

    const float2* __restrict__ Wl2 = (const float2*)Wl;
    const float2* __restrict__ Wr2 = (const float2*)Wr;
    const float2* __restrict__ bl2 = (const float2*)bl;

    float2 m = make_float2(0.f, 0.f);

    if (n0 < N) {
        float2 av[8], xv[8], o[8];
        float2 bv = bl2[lane];
#pragma unroll
        for (int q = 0; q < 8; ++q) {
            int n = n0 + q;
            if (n < N) { av[q] = agg2[n * 64 + lane]; xv[q] = x2[n * 64 + lane]; }
            else       { av[q] = make_float2(0.f, 0.f); xv[q] = make_float2(0.f, 0.f); }
            o[q] = bv;
        }
        for (int j = 0; j < 64; ++j) {
            float2 wl0 = Wl2[(2 * j) * 64 + lane];
            float2 wl1 = Wl2[(2 * j + 1) * 64 + lane];
            float2 wr0 = Wr2[(2 * j) * 64 + lane];
            float2 wr1 = Wr2[(2 * j + 1) * 64 + lane];
#pragma unroll
            for (int q = 0; q < 8; ++q) {
                float ax = __shfl(av[q].x, j);
                float ay = __shfl(av[q].y, j);
                float xx = __shfl(xv[q].x, j);
                float xy = __shfl(xv[q].y, j);
                o[q].x += ax * wl0.x + ay * wl1.x + xx * wr0.x + xy * wr1.x;
                o[q].y += ax * wl0.y + ay * wl1.y + xx * wr0.y + xy * wr1.y;
            }
        }
#pragma unroll
        for (int q = 0; q < 8; ++q) {
            if (n0 + q < N) {
                m.x = fmaxf(m.x, fmaxf(o[q].x, 0.f));
                m.y = fmaxf(m.y, fmaxf(o[q].y, 0.f));
            }
        }
    }

    __shared__ float2 red[4][64];
    red[wave][lane] = m;
    __syncthreads();
    if (wave == 0) {
#pragma unroll
        for (int ww = 1; ww < 4; ++ww) {
            m.x = fmaxf(m.x, red[ww][lane].x);
            m.y = fmaxf(m.y, red[ww][lane].y);
        }
        atomicMax(&hmaxU[2 * lane],     __float_as_uint(m.x));
        atomicMax(&hmaxU[2 * lane + 1], __float_as_uint(m.y));
    }
}

// ---- round-1 fallback fused kernel (used only if ws_size is too small) ----
__global__ __launch_bounds__(256) void k_agg_linmax(
    const float* __restrict__ x, const int* __restrict__ row_start,
    const int* __restrict__ csr, const float* __restrict__ Wl,
    const float* __restrict__ bl, const float* __restrict__ Wr,
    unsigned int* __restrict__ hmaxU, int N, int E) {
    const int lane = threadIdx.x & 63;
    const int wave = threadIdx.x >> 6;
    const int group = blockIdx.x * 4 + wave;
    const int ngroups = (N + 3) / 4;
    const float2* __restrict__ x2  = (const float2*)x;
    const float2* __restrict__ Wl2 = (const float2*)Wl;
    const float2* __restrict__ Wr2 = (const float2*)Wr;
    const float2* __restrict__ bl2 = (const float2*)bl;
    float2 m = make_float2(0.f, 0.f);
    if (group < ngroups) {
        int n0 = group * 4;
        int s[4], d[4];
#pragma unroll
        for (int q = 0; q < 4; ++q) {
            int n = n0 + q;
            if (n < N) { s[q] = row_start[n]; d[q] = row_start[n + 1] - s[q]; }
            else       { s[q] = 0; d[q] = 0; }
        }
        int maxd = max(max(d[0], d[1]), max(d[2], d[3]));
        float2 acc[4];
#pragma unroll
        for (int q = 0; q < 4; ++q) acc[q] = make_float2(0.f, 0.f);
        int idxv[4] = {0, 0, 0, 0};
        for (int i = 0; i < maxd; ++i) {
            int t = i & 63;
            if (t == 0) {
#pragma unroll
                for (int q = 0; q < 4; ++q) {
                    if (i < d[q]) {
                        int a = s[q] + i + lane;
                        a = (a < E) ? a : (E - 1);
                        idxv[q] = csr[a];
                    }
                }
            }
#pragma unroll
            for (int q = 0; q < 4; ++q) {
                if (i < d[q]) {
                    int src = __shfl(idxv[q], t);
                    float2 v = x2[src * 64 + lane];
                    acc[q].x += v.x; acc[q].y += v.y;
                }
            }
        }
        float2 xv[4];
#pragma unroll
        for (int q = 0; q < 4; ++q) {
            float sc = 1.0f / fmaxf((float)d[q], 1.0f);
            acc[q].x *= sc; acc[q].y *= sc;
            int n = n0 + q;
            xv[q] = (n < N) ? x2[n * 64 + lane] : make_float2(0.f, 0.f);
        }
        float2 o[4];
#pragma unroll
        for (int q = 0; q < 4; ++q) o[q] = bl2[lane];
        for (int j = 0; j < 64; ++j) {
            float2 wl0 = Wl2[(2 * j) * 64 + lane];
            float2 wl1 = Wl2[(2 * j + 1) * 64 + lane];
            float2 wr0 = Wr2[(2 * j) * 64 + lane];
            float2 wr1 = Wr2[(2 * j + 1) * 64 + lane];
#pragma unroll
            for (int q = 0; q < 4; ++q) {
                float ax = __shfl(acc[q].x, j);
                float ay = __shfl(acc[q].y, j);
                float xx = __shfl(xv[q].x, j);
                float xy = __shfl(xv[q].y, j);
                o[q].x += ax * wl0.x + ay * wl1.x + xx * wr0.x + xy * wr1.x;
                o[q].y += ax * wl0.y + ay * wl1.y + xx * wr0.y + xy * wr1.y;
            }
        }
#pragma unroll
        for (int q = 0; q < 4; ++q) {
            if (n0 + q < N) {
                m.x = fmaxf(m.x, fmaxf(o[q].x, 0.f));
                m.y = fmaxf(m.y, fmaxf(o[q].y, 0.f));
            }
        }
    }
    __shared__ float2 red[4][64];
    red[wave][lane] = m;
    __syncthreads();
    if (wave == 0) {
#pragma unroll
        for (int ww = 1; ww < 4; ++ww) {
            m.x = fmaxf(m.x, red[ww][lane].x);
            m.y = fmaxf(m.y, red[ww][lane].y);
        }
        atomicMax(&hmaxU[2 * lane],     __float_as_uint(m.x));
        atomicMax(&hmaxU[2 * lane + 1], __float_as_uint(m.y));
    }
}

// K5: tiny MLP head (single block, 128 threads)
__global__ void k_head(const float* __restrict__ x, const float* __restrict__ hmax,
                       const float* __restrict__ W0, const float* __restrict__ b0,
                       const float* __restrict__ W1, const float* __restrict__ b1,
                       const float* __restrict__ W2, const float* __restrict__ b2,
                       float* __restrict__ out) {
    __shared__ float s_cat[2 * NCH];
    __shared__ float s_h1[NCH];
    int t = threadIdx.x;  // 0..127
    float acc = b0[t];
    for (int k = 0; k < NCH; ++k) acc += x[k] * W0[k * NCH + t];
    s_cat[t] = fmaxf(acc, 0.f);       // news
    s_cat[NCH + t] = hmax[t];         // pooled h
    __syncthreads();
    float h = b1[t];
    for (int k = 0; k < 2 * NCH; ++k) h += s_cat[k] * W1[k * NCH + t];
    s_h1[t] = fmaxf(h, 0.f);
    __syncthreads();
    if (t < 2) {
        float o = b2[t];
        for (int k = 0; k < NCH; ++k) o += s_h1[k] * W2[k * 2 + t];
        out[t] = o;
    }
}

extern "C" void kernel_launch(void* const* d_in, const int* in_sizes, int n_in,
                              void* d_out, int out_size, void* d_ws, size_t ws_size,
                              hipStream_t stream) {
    const float* x  = (const float*)d_in[0];
    const void*  ei = d_in[1];
    const float* Wl = (const float*)d_in[2];
    const float* bl = (const float*)d_in[3];
    const float* Wr = (const float*)d_in[4];
    const float* W0 = (const float*)d_in[5];
    const float* b0 = (const float*)d_in[6];
    const float* W1 = (const float*)d_in[7];
    const float* b1 = (const float*)d_in[8];
    const float* W2 = (const float*)d_in[9];
    const float* b2 = (const float*)d_in[10];
    float* out = (float*)d_out;

    const int N = in_sizes[0] / NCH;   // 10000
    const int E = in_sizes[1] / 2;     // 640000

    // workspace layout (ints):
    // [0, N)             cnt
    // [N, 2N)            cursor
    // [2N, 2N+128)       hmax (uint-as-float)
    // [2N+128..2N+131]   flag (+pad)
    // [2N+132, 3N+133)   row_start (N+1), pad to 3N+136
    // [3N+136, 3N+136+E) csr_src
    // then xb (N*64 uints), then agg (N*128 floats)
    int* iws       = (int*)d_ws;
    int* cnt       = iws;
    int* cursor    = iws + N;
    unsigned int* hmaxU = (unsigned int*)(iws + 2 * N);
    int* flag      = iws + 2 * N + 128;
    int* row_start = iws + 2 * N + 132;
    int* csr       = iws + 3 * N + 136;
    unsigned int* xb = (unsigned int*)(csr + E);
    float* agg     = (float*)(xb + (size_t)N * 64);

    size_t need_full = ((size_t)(3 * N + 136) + E + (size_t)N * 64 + (size_t)N * 128) * 4;
    bool full = ws_size >= need_full;

    hipMemsetAsync(d_ws, 0, (size_t)(2 * N + 132) * sizeof(int), stream);

    k_detect<<<1, 64, 0, stream>>>((const int*)ei, flag);
    k_hist<<<(E + 255) / 256, 256, 0, stream>>>((const int*)ei, (const long long*)ei,
                                                flag, cnt, E);
    k_scan<<<1, 1024, 0, stream>>>(cnt, row_start, N);
    k_fill<<<(E + 255) / 256, 256, 0, stream>>>((const int*)ei, (const long long*)ei,
                                                flag, row_start, cursor, csr, E);
    if (full) {
        int n2 = N * 64;
        k_cast<<<(n2 + 255) / 256, 256, 0, stream>>>((const float2*)x, xb, n2);
        k_agg<<<(N + 3) / 4, 256, 0, stream>>>(xb, row_start, csr, (float2*)agg, N);
        int nwaves = (N + 7) / 8;
        k_dense<<<(nwaves + 3) / 4, 256, 0, stream>>>((const float2*)x, (const float2*)agg,
                                                      Wl, bl, Wr, hmaxU, N);
    } else {
        int ngroups = (N + 3) / 4;
        k_agg_linmax<<<(ngroups + 3) / 4, 256, 0, stream>>>(x, row_start, csr, Wl, bl, Wr,
                                                            hmaxU, N, E);
    }
    k_head<<<1, 128, 0, stream>>>(x, (const float*)hmaxU, W0, b0, W1, b1, W2, b2, out);
}

// Round 3
// 216.695 us; speedup vs baseline: 1.4301x; 1.1977x over previous
//
#include <hip/hip_runtime.h>
#include <hip/hip_bf16.h>

#define NCH 128   // IN_CH == HID == 128

typedef __attribute__((ext_vector_type(8))) short bfrag;   // 8 bf16 (4 VGPRs)
typedef __attribute__((ext_vector_type(4))) float ffrag;   // 4 fp32 acc

// ---------------------------------------------------------------------------
// K0: detect edge_index storage width. If stored as int64 (little-endian,
// values < 2^31), every odd int32 word of the first 64 elements is 0.
__global__ void k_detect(const int* __restrict__ ei, int* __restrict__ flag) {
    int v = ei[2 * threadIdx.x + 1];
    unsigned long long b = __ballot(v != 0);
    if (threadIdx.x == 0) *flag = (b == 0ULL) ? 1 : 0;
}

// fp32 pair -> packed bf16 pair (RNE); .x in low 16 bits
__device__ inline unsigned int f2bf_pair(float lo, float hi) {
    unsigned int ul = __float_as_uint(lo);
    unsigned int uh = __float_as_uint(hi);
    ul = (ul + 0x7fffu + ((ul >> 16) & 1u)) >> 16;
    uh = (uh + 0x7fffu + ((uh >> 16) & 1u)) & 0xffff0000u;
    return (ul & 0xffffu) | uh;
}

// K_cast: write bf16(x) into the x-half of M ([N][256] bf16, pairs as uint).
// M32[n*128 + 64 + c] = pair(x[n][2c], x[n][2c+1])
__global__ void k_cast(const float2* __restrict__ x2, unsigned int* __restrict__ M32, int n2) {
    int i = blockIdx.x * blockDim.x + threadIdx.x;
    if (i >= n2) return;
    float2 v = x2[i];
    int n = i >> 6, c = i & 63;
    M32[n * 128 + 64 + c] = f2bf_pair(v.x, v.y);
}

// K_prepw: Wt[c][k] = bf16(Wcat[k][c]), Wcat = [Wl; Wr]  (B-fragment layout)
// stored as pairs: Wt32[c*128 + kp] covers k = 2kp, 2kp+1
__global__ void k_prepw(const float* __restrict__ Wl, const float* __restrict__ Wr,
                        unsigned int* __restrict__ Wt32) {
    int i = blockIdx.x * blockDim.x + threadIdx.x;   // 0 .. 128*128-1
    if (i >= 128 * 128) return;
    int c = i & 127, kp = i >> 7;
    int k0 = 2 * kp, k1 = 2 * kp + 1;
    float v0 = (k0 < 128) ? Wl[k0 * 128 + c] : Wr[(k0 - 128) * 128 + c];
    float v1 = (k1 < 128) ? Wl[k1 * 128 + c] : Wr[(k1 - 128) * 128 + c];
    Wt32[c * 128 + kp] = f2bf_pair(v0, v1);
}

// K1: histogram of destination degrees
__global__ void k_hist(const int* __restrict__ ei32, const long long* __restrict__ ei64,
                       const int* __restrict__ flag, int* __restrict__ cnt, int E) {
    int e = blockIdx.x * blockDim.x + threadIdx.x;
    if (e >= E) return;
    int dst = (*flag) ? (int)ei64[(size_t)E + e] : ei32[(size_t)E + e];
    atomicAdd(&cnt[dst], 1);
}

// K2: exclusive scan of cnt -> row_start (single block, 1024 threads)
__global__ void k_scan(const int* __restrict__ cnt, int* __restrict__ row_start, int N) {
    __shared__ int lds[1024];
    int t = threadIdx.x;
    int chunk = (N + 1023) / 1024;
    int base = t * chunk;
    int sum = 0;
    for (int i = 0; i < chunk; ++i) {
        int idx = base + i;
        if (idx < N) sum += cnt[idx];
    }
    lds[t] = sum;
    __syncthreads();
    for (int off = 1; off < 1024; off <<= 1) {
        int v = (t >= off) ? lds[t - off] : 0;
        __syncthreads();
        lds[t] += v;
        __syncthreads();
    }
    int run = (t == 0) ? 0 : lds[t - 1];
    for (int i = 0; i < chunk; ++i) {
        int idx = base + i;
        if (idx < N) { row_start[idx] = run; run += cnt[idx]; }
    }
    if (t == 1023) row_start[N] = run;
}

// K3: fill CSR source lists
__global__ void k_fill(const int* __restrict__ ei32, const long long* __restrict__ ei64,
                       const int* __restrict__ flag, const int* __restrict__ row_start,
                       int* __restrict__ cursor, int* __restrict__ csr, int E) {
    int e = blockIdx.x * blockDim.x + threadIdx.x;
    if (e >= E) return;
    int src, dst;
    if (*flag) { src = (int)ei64[e]; dst = (int)ei64[(size_t)E + e]; }
    else       { src = ei32[e];      dst = ei32[(size_t)E + e]; }
    int pos = atomicAdd(&cursor[dst], 1);
    csr[row_start[dst] + pos] = src;
}

// K4a: pull aggregation, 1 node per wave; gathers bf16 x from M's x-half,
// fp32 accumulate, writes bf16 agg into M's agg-half.
__global__ __launch_bounds__(256) void k_agg(
    unsigned int* __restrict__ M32, const int* __restrict__ row_start,
    const int* __restrict__ csr, int N) {
    const int lane = threadIdx.x & 63;
    const int node = blockIdx.x * 4 + (threadIdx.x >> 6);
    if (node >= N) return;
    int s = row_start[node];
    int e = row_start[node + 1];
    int d = e - s;
    float ax = 0.f, ay = 0.f;
    for (int base = s; base < e; base += 64) {
        int cnt = min(64, e - base);
        int idx = csr[base + min(lane, cnt - 1)];
        int i = 0;
        for (; i + 8 <= cnt; i += 8) {
            int srcs[8];
#pragma unroll
            for (int j = 0; j < 8; ++j) srcs[j] = __shfl(idx, i + j);
            unsigned int us[8];
#pragma unroll
            for (int j = 0; j < 8; ++j) us[j] = M32[srcs[j] * 128 + 64 + lane];
#pragma unroll
            for (int j = 0; j < 8; ++j) {
                ax += __uint_as_float(us[j] << 16);
                ay += __uint_as_float(us[j] & 0xffff0000u);
            }
        }
        for (; i < cnt; ++i) {
            int src = __shfl(idx, i);
            unsigned int u = M32[src * 128 + 64 + lane];
            ax += __uint_as_float(u << 16);
            ay += __uint_as_float(u & 0xffff0000u);
        }
    }
    float sc = 1.0f / fmaxf((float)d, 1.0f);
    M32[node * 128 + lane] = f2bf_pair(ax * sc, ay * sc);
}

// K4b: MFMA dense: h = relu(M @ Wcat + bl); column max over all rows.
// One wave = one 16-row tile x all 128 cols (8 col-tiles), K=256 (8 MFMAs/ctile).
// A layout: lane holds A[m=lane&15][k=quad*8+j]; C/D: col=lane&15, row=quad*4+reg.
__global__ __launch_bounds__(256) void k_dense_mfma(
    const short* __restrict__ M,    // [N][256] bf16
    const short* __restrict__ Wt,   // [128 cols][256 k] bf16
    const float* __restrict__ bl,
    unsigned int* __restrict__ hmaxU, int N) {
    const int lane = threadIdx.x & 63;
    const int wave = threadIdx.x >> 6;
    const int tile = blockIdx.x * 4 + wave;
    const int ntiles = (N + 15) / 16;
    const int l16  = lane & 15;
    const int quad = lane >> 4;

    float mx[8];
#pragma unroll
    for (int c = 0; c < 8; ++c) mx[c] = 0.f;

    if (tile < ntiles) {
        int m = tile * 16 + l16;
        int mc = min(m, N - 1);
        bfrag a[8];
#pragma unroll
        for (int kk = 0; kk < 8; ++kk)
            a[kk] = *(const bfrag*)(M + (size_t)mc * 256 + kk * 32 + quad * 8);

#pragma unroll
        for (int c = 0; c < 8; ++c) {
            int col = c * 16 + l16;
            float bv = bl[col];
            ffrag acc = {bv, bv, bv, bv};
            const short* wp = Wt + (size_t)col * 256 + quad * 8;
#pragma unroll
            for (int kk = 0; kk < 8; ++kk) {
                bfrag b = *(const bfrag*)(wp + kk * 32);
                acc = __builtin_amdgcn_mfma_f32_16x16x32_bf16(a[kk], b, acc, 0, 0, 0);
            }
            float lm = 0.f;
#pragma unroll
            for (int r = 0; r < 4; ++r) {
                int row = tile * 16 + quad * 4 + r;
                float v = fmaxf(acc[r], 0.f);
                if (row < N) lm = fmaxf(lm, v);
            }
            mx[c] = lm;
        }
#pragma unroll
        for (int c = 0; c < 8; ++c) {
            mx[c] = fmaxf(mx[c], __shfl_xor(mx[c], 16));
            mx[c] = fmaxf(mx[c], __shfl_xor(mx[c], 32));
        }
    }

    __shared__ float red[4][128];
    if (lane < 16) {
#pragma unroll
        for (int c = 0; c < 8; ++c) red[wave][c * 16 + lane] = mx[c];
    }
    __syncthreads();
    if (wave == 0) {
        for (int i = lane; i < 128; i += 64) {
            float v = fmaxf(fmaxf(red[0][i], red[1][i]), fmaxf(red[2][i], red[3][i]));
            atomicMax(&hmaxU[i], __float_as_uint(v));
        }
    }
}

// ---- round-1 fallback fused kernel (used only if ws_size is too small) ----
__global__ __launch_bounds__(256) void k_agg_linmax(
    const float* __restrict__ x, const int* __restrict__ row_start,
    const int* __restrict__ csr, const float* __restrict__ Wl,
    const float* __restrict__ bl, const float* __restrict__ Wr,
    unsigned int* __restrict__ hmaxU, int N, int E) {
    const int lane = threadIdx.x & 63;
    const int wave = threadIdx.x >> 6;
    const int group = blockIdx.x * 4 + wave;
    const int ngroups = (N + 3) / 4;
    const float2* __restrict__ x2  = (const float2*)x;
    const float2* __restrict__ Wl2 = (const float2*)Wl;
    const float2* __restrict__ Wr2 = (const float2*)Wr;
    const float2* __restrict__ bl2 = (const float2*)bl;
    float2 m = make_float2(0.f, 0.f);
    if (group < ngroups) {
        int n0 = group * 4;
        int s[4], d[4];
#pragma unroll
        for (int q = 0; q < 4; ++q) {
            int n = n0 + q;
            if (n < N) { s[q] = row_start[n]; d[q] = row_start[n + 1] - s[q]; }
            else       { s[q] = 0; d[q] = 0; }
        }
        int maxd = max(max(d[0], d[1]), max(d[2], d[3]));
        float2 acc[4];
#pragma unroll
        for (int q = 0; q < 4; ++q) acc[q] = make_float2(0.f, 0.f);
        int idxv[4] = {0, 0, 0, 0};
        for (int i = 0; i < maxd; ++i) {
            int t = i & 63;
            if (t == 0) {
#pragma unroll
                for (int q = 0; q < 4; ++q) {
                    if (i < d[q]) {
                        int a = s[q] + i + lane;
                        a = (a < E) ? a : (E - 1);
                        idxv[q] = csr[a];
                    }
                }
            }
#pragma unroll
            for (int q = 0; q < 4; ++q) {
                if (i < d[q]) {
                    int src = __shfl(idxv[q], t);
                    float2 v = x2[src * 64 + lane];
                    acc[q].x += v.x; acc[q].y += v.y;
                }
            }
        }
        float2 xv[4];
#pragma unroll
        for (int q = 0; q < 4; ++q) {
            float sc = 1.0f / fmaxf((float)d[q], 1.0f);
            acc[q].x *= sc; acc[q].y *= sc;
            int n = n0 + q;
            xv[q] = (n < N) ? x2[n * 64 + lane] : make_float2(0.f, 0.f);
        }
        float2 o[4];
#pragma unroll
        for (int q = 0; q < 4; ++q) o[q] = bl2[lane];
        for (int j = 0; j < 64; ++j) {
            float2 wl0 = Wl2[(2 * j) * 64 + lane];
            float2 wl1 = Wl2[(2 * j + 1) * 64 + lane];
            float2 wr0 = Wr2[(2 * j) * 64 + lane];
            float2 wr1 = Wr2[(2 * j + 1) * 64 + lane];
#pragma unroll
            for (int q = 0; q < 4; ++q) {
                float ax = __shfl(acc[q].x, j);
                float ay = __shfl(acc[q].y, j);
                float xx = __shfl(xv[q].x, j);
                float xy = __shfl(xv[q].y, j);
                o[q].x += ax * wl0.x + ay * wl1.x + xx * wr0.x + xy * wr1.x;
                o[q].y += ax * wl0.y + ay * wl1.y + xx * wr0.y + xy * wr1.y;
            }
        }
#pragma unroll
        for (int q = 0; q < 4; ++q) {
            if (n0 + q < N) {
                m.x = fmaxf(m.x, fmaxf(o[q].x, 0.f));
                m.y = fmaxf(m.y, fmaxf(o[q].y, 0.f));
            }
        }
    }
    __shared__ float2 red[4][64];
    red[wave][lane] = m;
    __syncthreads();
    if (wave == 0) {
#pragma unroll
        for (int ww = 1; ww < 4; ++ww) {
            m.x = fmaxf(m.x, red[ww][lane].x);
            m.y = fmaxf(m.y, red[ww][lane].y);
        }
        atomicMax(&hmaxU[2 * lane],     __float_as_uint(m.x));
        atomicMax(&hmaxU[2 * lane + 1], __float_as_uint(m.y));
    }
}

// K5: tiny MLP head (single block, 128 threads)
__global__ void k_head(const float* __restrict__ x, const float* __restrict__ hmax,
                       const float* __restrict__ W0, const float* __restrict__ b0,
                       const float* __restrict__ W1, const float* __restrict__ b1,
                       const float* __restrict__ W2, const float* __restrict__ b2,
                       float* __restrict__ out) {
    __shared__ float s_cat[2 * NCH];
    __shared__ float s_h1[NCH];
    int t = threadIdx.x;  // 0..127
    float acc = b0[t];
    for (int k = 0; k < NCH; ++k) acc += x[k] * W0[k * NCH + t];
    s_cat[t] = fmaxf(acc, 0.f);       // news
    s_cat[NCH + t] = hmax[t];         // pooled h
    __syncthreads();
    float h = b1[t];
    for (int k = 0; k < 2 * NCH; ++k) h += s_cat[k] * W1[k * NCH + t];
    s_h1[t] = fmaxf(h, 0.f);
    __syncthreads();
    if (t < 2) {
        float o = b2[t];
        for (int k = 0; k < NCH; ++k) o += s_h1[k] * W2[k * 2 + t];
        out[t] = o;
    }
}

extern "C" void kernel_launch(void* const* d_in, const int* in_sizes, int n_in,
                              void* d_out, int out_size, void* d_ws, size_t ws_size,
                              hipStream_t stream) {
    const float* x  = (const float*)d_in[0];
    const void*  ei = d_in[1];
    const float* Wl = (const float*)d_in[2];
    const float* bl = (const float*)d_in[3];
    const float* Wr = (const float*)d_in[4];
    const float* W0 = (const float*)d_in[5];
    const float* b0 = (const float*)d_in[6];
    const float* W1 = (const float*)d_in[7];
    const float* b1 = (const float*)d_in[8];
    const float* W2 = (const float*)d_in[9];
    const float* b2 = (const float*)d_in[10];
    float* out = (float*)d_out;

    const int N = in_sizes[0] / NCH;   // 10000
    const int E = in_sizes[1] / 2;     // 640000

    // workspace layout (ints):
    // [0, N)             cnt
    // [N, 2N)            cursor
    // [2N, 2N+128)       hmax (uint-as-float)
    // [2N+128..2N+131]   flag (+pad)
    // [2N+132, 3N+133)   row_start (N+1), pad to 3N+136
    // [3N+136, +E)       csr_src
    // then Wt (128*128 uints = 64 KB), then M (N*128 uints, [N][256] bf16)
    int* iws       = (int*)d_ws;
    int* cnt       = iws;
    int* cursor    = iws + N;
    unsigned int* hmaxU = (unsigned int*)(iws + 2 * N);
    int* flag      = iws + 2 * N + 128;
    int* row_start = iws + 2 * N + 132;
    int* csr       = iws + 3 * N + 136;
    unsigned int* Wt32 = (unsigned int*)(csr + E);
    unsigned int* M32  = Wt32 + 128 * 128;

    size_t need_full = ((size_t)(3 * N + 136) + E + 128 * 128 + (size_t)N * 128) * 4;
    bool full = ws_size >= need_full;

    hipMemsetAsync(d_ws, 0, (size_t)(2 * N + 132) * sizeof(int), stream);

    k_detect<<<1, 64, 0, stream>>>((const int*)ei, flag);
    k_hist<<<(E + 255) / 256, 256, 0, stream>>>((const int*)ei, (const long long*)ei,
                                                flag, cnt, E);
    k_scan<<<1, 1024, 0, stream>>>(cnt, row_start, N);
    k_fill<<<(E + 255) / 256, 256, 0, stream>>>((const int*)ei, (const long long*)ei,
                                                flag, row_start, cursor, csr, E);
    if (full) {
        int n2 = N * 64;
        k_cast<<<(n2 + 255) / 256, 256, 0, stream>>>((const float2*)x, M32, n2);
        k_prepw<<<(128 * 128 + 255) / 256, 256, 0, stream>>>(Wl, Wr, Wt32);
        k_agg<<<(N + 3) / 4, 256, 0, stream>>>(M32, row_start, csr, N);
        int ntiles = (N + 15) / 16;
        k_dense_mfma<<<(ntiles + 3) / 4, 256, 0, stream>>>((const short*)M32,
                                                           (const short*)Wt32,
                                                           bl, hmaxU, N);
    } else {
        int ngroups = (N + 3) / 4;
        k_agg_linmax<<<(ngroups + 3) / 4, 256, 0, stream>>>(x, row_start, csr, Wl, bl, Wr,
                                                            hmaxU, N, E);
    }
    k_head<<<1, 128, 0, stream>>>(x, (const float*)hmaxU, W0, b0, W1, b1, W2, b2, out);
}